// Round 4
// baseline (81.277 us; speedup 1.0000x reference)
//
#include <hip/hip_runtime.h>

#define NHEAD 8
#define SEQL  32
static constexpr float W_MUL = 0.632455532033675866f;  // sqrt(2/5)
static constexpr float PI_F  = 3.14159265358979323846f;

__device__ __forceinline__ float2 cmulf(float2 a, float2 b) {
    return make_float2(a.x*b.x - a.y*b.y, a.x*b.y + a.y*b.x);
}
__device__ __forceinline__ float2 caddf(float2 a, float2 b) {
    return make_float2(a.x + b.x, a.y + b.y);
}
// sigma(a) = (a2, a1^a2, a0^a1): hi-part linear map of the CNOT-ring inverse
__device__ __forceinline__ int sig3(int a) {
    int a2=(a>>2)&1, a1=(a>>1)&1, a0=a&1;
    return (a2<<2) | ((a1^a2)<<1) | (a0^a1);
}

// ---------------------------------------------------------------------------
// Fully fused: one kernel, 32 blocks (one per sequence position i) x 512
// threads (8 waves, wave = head h). Each block computes its entire dependency
// cone locally (psi, U8 unitaries, Q[h,i], K[h,:], chain coeffs, serial
// recurrence, output row) -- no inter-kernel launches or grid sync.
// ---------------------------------------------------------------------------
__global__ __launch_bounds__(512) void kfused(const float* __restrict__ x,
                                              const float* __restrict__ pqc_w,
                                              const float* __restrict__ W1,
                                              const float* __restrict__ b1,
                                              const float* __restrict__ W2,
                                              const float* __restrict__ b2,
                                              float* __restrict__ out) {
    __shared__ float  xq[SEQL][8];
    __shared__ float  psi[SEQL][8];
    __shared__ float2 us[NHEAD][9][4];           // [h][g*3+q][2x2 entries]
    __shared__ float2 U8s[NHEAD][3][64];         // [h][g][r*8+c]
    __shared__ __align__(16) float2 Carr[NHEAD][SEQL][4][2]; // [h][j][a0*2+c0][par]
    __shared__ float2 w0s[NHEAD][8];
    __shared__ float  Zs[NHEAD][8];

    const int t = threadIdx.x;
    const int l = t & 63;        // lane within wave
    const int h = t >> 6;        // wave index = head
    const int i = blockIdx.x;    // sequence position

    // ---- Phase A1: xq[s][k] = x[s]·W1[k] + b1[k]  (threads 0..255) ----
    if (t < 256) {
        const int s = t >> 3, k = t & 7;
        const float4* xr = (const float4*)(x  + s*64);
        const float4* wr = (const float4*)(W1 + k*64);
        float acc = b1[k];
        #pragma unroll
        for (int q = 0; q < 16; ++q) {
            float4 xa = xr[q], wa = wr[q];
            acc += xa.x*wa.x + xa.y*wa.y + xa.z*wa.z + xa.w*wa.w;
        }
        xq[s][k] = acc;
    }
    // ---- Phase B1: per-qubit 2x2 unitaries (lanes 0..8 of each wave) ----
    if (l < 9) {
        const int g = l / 3, q = l % 3;
        const int base = h*27 + g*9 + q*3;
        float t0 = pqc_w[base+0] * W_MUL;
        float t1 = pqc_w[base+1] * W_MUL;
        float t2 = pqc_w[base+2] * W_MUL;
        float c0, s0, c1, s1, cz, sz;
        sincosf(t0*0.5f, &s0, &c0);
        sincosf(t1*0.5f, &s1, &c1);
        sincosf(t2*0.5f, &sz, &cz);
        float2 m00 = make_float2(c1*c0,  s1*s0);
        float2 m01 = make_float2(-s1*c0, -c1*s0);
        float2 m10 = make_float2(s1*c0,  -c1*s0);
        float2 m11 = make_float2(c1*c0,  -s1*s0);
        float2 em = make_float2(cz, -sz), ep = make_float2(cz, sz);
        us[h][l][0] = cmulf(em, m00);
        us[h][l][1] = cmulf(em, m01);
        us[h][l][2] = cmulf(ep, m10);
        us[h][l][3] = cmulf(ep, m11);
    }
    __syncthreads();

    // ---- Phase A2: psi = row-normalize(xq) ----
    if (t < 256) {
        const int s = t >> 3, k = t & 7;
        float ss = 0.f;
        #pragma unroll
        for (int kk = 0; kk < 8; ++kk) ss += xq[s][kk]*xq[s][kk];
        psi[s][k] = xq[s][k] * rsqrtf(ss);
    }
    // ---- Phase B2: U8 = u0 ⊗ u1 ⊗ u2 per (h,g), lane = (r,c) ----
    {
        const int r = l >> 3, c = l & 7;
        const int i0 = ((r>>2)<<1)       | (c>>2);
        const int i1 = (((r>>1)&1)<<1)   | ((c>>1)&1);
        const int i2 = ((r&1)<<1)        | (c&1);
        #pragma unroll
        for (int g = 0; g < 3; ++g)
            U8s[h][g][l] = cmulf(cmulf(us[h][g*3+0][i0], us[h][g*3+1][i1]),
                                 us[h][g*3+2][i2]);
    }
    __syncthreads();

    // ---- Phase C: per lane (j = l>>1, half = l&1) build chain coeffs ----
    {
        const int j = l >> 1, half = l & 1;

        // Q[h,i] (redundant per lane; A = UC6^T MZ6 UC6 is diagonal, sA = a2^a0)
        float qhi = 0.f;
        #pragma unroll
        for (int a = 0; a < 8; ++a) {
            float2 ph = make_float2(0.f, 0.f);
            #pragma unroll
            for (int b = 0; b < 8; ++b) {
                float pb = psi[i][b];
                float2 ue = U8s[h][0][a*8 + b];
                ph.x += ue.x * pb;
                ph.y += ue.y * pb;
            }
            float sign = (((a>>2) ^ a) & 1) ? -1.f : 1.f;
            qhi += sign * (ph.x*ph.x + ph.y*ph.y);
        }
        // K[h,j]: this lane does components a = half*4 .. half*4+3 (sB = b1)
        float kj;
        {
            float acc = 0.f;
            #pragma unroll
            for (int aa = 0; aa < 4; ++aa) {
                int a = half*4 + aa;
                float2 ph = make_float2(0.f, 0.f);
                #pragma unroll
                for (int b = 0; b < 8; ++b) {
                    float pb = psi[j][b];
                    float2 ue = U8s[h][1][a*8 + b];
                    ph.x += ue.x * pb;
                    ph.y += ue.y * pb;
                }
                float sign = ((a>>1) & 1) ? -1.f : 1.f;
                acc += sign * (ph.x*ph.x + ph.y*ph.y);
            }
            kj = acc + __shfl_xor(acc, 1, 64);
        }
        // vphi_j = U8_v psi_j (all 8 components)
        float2 w[8];
        #pragma unroll
        for (int a = 0; a < 8; ++a) {
            float2 ph = make_float2(0.f, 0.f);
            #pragma unroll
            for (int b = 0; b < 8; ++b) {
                float pb = psi[j][b];
                float2 ue = U8s[h][2][a*8 + b];
                ph.x += ue.x * pb;
                ph.y += ue.y * pb;
            }
            w[a] = ph;
        }
        // u1 = rz(phi) @ ry(phi/2) @ rx(phi/2), phi = pi * Q * K_j
        float phi = PI_F * qhi * kj;
        float c1, s1, ch, sh;
        sincosf(phi*0.25f, &s1, &c1);
        sincosf(phi*0.5f,  &sh, &ch);
        float2 em = make_float2(ch, -sh), ep = make_float2(ch, sh);
        float sc = s1*c1;
        float2 u00 = cmulf(em, make_float2(c1*c1,  s1*s1));
        float2 u01 = cmulf(em, make_float2(-sc, -sc));
        float2 u10 = cmulf(ep, make_float2(sc, -sc));
        float2 u11 = cmulf(ep, make_float2(c1*c1, -s1*s1));

        // w = (u1 ⊗ u1 ⊗ u1) vphi_j
        #pragma unroll
        for (int p = 0; p < 4; ++p) {            // qubit 0 (MSB), stride 4
            float2 lo = w[p], hi = w[p+4];
            w[p]   = caddf(cmulf(u00, lo), cmulf(u01, hi));
            w[p+4] = caddf(cmulf(u10, lo), cmulf(u11, hi));
        }
        #pragma unroll
        for (int p = 0; p < 4; ++p) {            // qubit 1, stride 2
            int i0 = ((p >> 1) << 2) | (p & 1);  // 0,1,4,5
            float2 lo = w[i0], hi = w[i0+2];
            w[i0]   = caddf(cmulf(u00, lo), cmulf(u01, hi));
            w[i0+2] = caddf(cmulf(u10, lo), cmulf(u11, hi));
        }
        #pragma unroll
        for (int p = 0; p < 4; ++p) {            // qubit 2 (LSB), stride 1
            float2 lo = w[2*p], hi = w[2*p+1];
            w[2*p]   = caddf(cmulf(u00, lo), cmulf(u01, hi));
            w[2*p+1] = caddf(cmulf(u10, lo), cmulf(u11, hi));
        }

        if (l == 0) {                             // j==0, half==0
            #pragma unroll
            for (int b = 0; b < 8; ++b) w0s[h][b] = w[b];
        }
        // C_{half}(a0,c0) = sum_{par(m)=half} w[4a0^m] conj(w[4c0^m])
        const int mset0[4] = {0,3,5,6}, mset1[4] = {1,2,4,7};
        #pragma unroll
        for (int combo = 0; combo < 4; ++combo) {
            int a0 = combo >> 1, c0 = combo & 1;
            float2 acc = make_float2(0.f, 0.f);
            #pragma unroll
            for (int tt = 0; tt < 4; ++tt) {
                int m = half ? mset1[tt] : mset0[tt];
                float2 wx = w[(a0<<2)^m], wy = w[(c0<<2)^m];
                acc.x += wx.x*wy.x + wx.y*wy.y;   // w[x]·conj(w[y])
                acc.y += wx.y*wy.x - wx.x*wy.y;
            }
            Carr[h][j][combo][half] = acc;
        }
    }
    __syncthreads();

    // ---- Phase D: serial chain (per wave); lane holds rho[a][c] ----
    {
        const int a = l >> 3, c = l & 7;
        const int combo = ((a & 1) << 1) | (c & 1);
        const int src0 = (sig3(a) << 3) | sig3(c);
        const int src1 = src0 ^ 54;               // ^ (6<<3 | 6)

        float2 wa = w0s[h][a], wc = w0s[h][c];
        float rr = wa.x*wc.x + wa.y*wc.y;         // rho = w0 w0†
        float ri = wa.y*wc.x - wa.x*wc.y;

        for (int j = 1; j < SEQL; ++j) {
            float4 Cv = *((const float4*)&Carr[h][j][combo][0]);
            float R0r = __shfl(rr, src0, 64);
            float R0i = __shfl(ri, src0, 64);
            float R1r = __shfl(rr, src1, 64);
            float R1i = __shfl(ri, src1, 64);
            float nr = Cv.x*R0r - Cv.y*R0i + Cv.z*R1r - Cv.w*R1i;
            float ni = Cv.x*R0i + Cv.y*R0r + Cv.z*R1i + Cv.w*R1r;
            rr = nr; ri = ni;
        }
        if (a == c) Zs[h][a] = rr;
    }
    __syncthreads();

    // ---- Phase E: out[i,m] = b2[m] + sum_c Zs[c>>3][c&7] * W2[m,c] ----
    {
        const int m = t >> 3, p = t & 7;
        float acc = 0.f;
        #pragma unroll
        for (int cc = 0; cc < 8; ++cc)
            acc += Zs[p][cc] * W2[m*64 + p*8 + cc];
        acc += __shfl_xor(acc, 1, 64);
        acc += __shfl_xor(acc, 2, 64);
        acc += __shfl_xor(acc, 4, 64);
        if (p == 0) out[i*64 + m] = acc + b2[m];
    }
}

extern "C" void kernel_launch(void* const* d_in, const int* in_sizes, int n_in,
                              void* d_out, int out_size, void* d_ws, size_t ws_size,
                              hipStream_t stream) {
    const float* x     = (const float*)d_in[0];
    const float* pqc_w = (const float*)d_in[1];
    const float* W1    = (const float*)d_in[2];
    const float* b1    = (const float*)d_in[3];
    const float* W2    = (const float*)d_in[4];
    const float* b2    = (const float*)d_in[5];
    // d_in[6] = edge_index (unused)

    hipLaunchKernelGGL(kfused, dim3(SEQL), dim3(512), 0, stream,
                       x, pqc_w, W1, b1, W2, b2, (float*)d_out);
}

// Round 5
// 79.941 us; speedup vs baseline: 1.0167x; 1.0167x over previous
//
#include <hip/hip_runtime.h>

#define NHEAD 8
#define SEQL  32
static constexpr float W_MUL = 0.632455532033675866f;  // sqrt(2/5)
static constexpr float PI_F  = 3.14159265358979323846f;

__device__ __forceinline__ float2 cmulf(float2 a, float2 b) {
    return make_float2(a.x*b.x - a.y*b.y, a.x*b.y + a.y*b.x);
}
__device__ __forceinline__ float2 caddf(float2 a, float2 b) {
    return make_float2(a.x + b.x, a.y + b.y);
}
// sigma(a) = (a2, a1^a2, a0^a1): hi-part linear map of the CNOT-ring inverse
__device__ __forceinline__ int sig3(int a) {
    int a2=(a>>2)&1, a1=(a>>1)&1, a0=a&1;
    return (a2<<2) | ((a1^a2)<<1) | (a0^a1);
}

// ---------------------------------------------------------------------------
// Fully fused, lean version: 32 blocks (one per seq position i) x 512 threads
// (8 waves, wave = head h). vs round 4: Q/K/V transforms distributed across
// lanes (not redundant per-lane), hardware __sinf/__cosf instead of libm
// sincosf, W2/b2 prefetched into registers at kernel entry.
// ---------------------------------------------------------------------------
__global__ __launch_bounds__(512) void kfused(const float* __restrict__ x,
                                              const float* __restrict__ pqc_w,
                                              const float* __restrict__ W1,
                                              const float* __restrict__ b1,
                                              const float* __restrict__ W2,
                                              const float* __restrict__ b2,
                                              float* __restrict__ out) {
    __shared__ float  xq[SEQL][8];
    __shared__ float  psi[SEQL][8];
    __shared__ float2 us[NHEAD][9][4];            // [h][g*3+q][2x2 entries]
    __shared__ float2 U8s[NHEAD][3][64];          // [h][g][a*8+b]
    __shared__ float  Ks[NHEAD][SEQL];
    __shared__ float  Qs[NHEAD];
    __shared__ __align__(16) float2 Vs[NHEAD][SEQL][8];
    __shared__ __align__(16) float2 Carr[NHEAD][SEQL][4][2]; // [h][j][a0*2+c0][par]
    __shared__ float2 w0s[NHEAD][8];
    __shared__ float  Zs[NHEAD][8];

    const int t = threadIdx.x;
    const int l = t & 63;        // lane within wave
    const int h = t >> 6;        // wave index = head
    const int i = blockIdx.x;    // sequence position

    // ---- Prefetch W2 fragment + b2 for Phase E (latency hidden behind A-D) --
    const int mE = t >> 3, pE = t & 7;
    const float4 w2a = *(const float4*)(W2 + mE*64 + pE*8);
    const float4 w2b = *(const float4*)(W2 + mE*64 + pE*8 + 4);
    const float  b2m = b2[mE];

    // ---- Phase A1: xq[s][k] = x[s]·W1[k] + b1[k]; 2 threads per dot ----
    {
        const int s = t >> 4, k = (t >> 1) & 7, hf = t & 1;
        const float4* xr = (const float4*)(x  + s*64) + hf*8;
        const float4* wr = (const float4*)(W1 + k*64) + hf*8;
        float acc = hf ? 0.f : b1[k];
        #pragma unroll
        for (int q = 0; q < 8; ++q) {
            float4 xa = xr[q], wa = wr[q];
            acc += xa.x*wa.x + xa.y*wa.y + xa.z*wa.z + xa.w*wa.w;
        }
        acc += __shfl_xor(acc, 1, 64);
        if (!hf) xq[s][k] = acc;
    }
    // ---- Phase B1: per-qubit 2x2 unitaries (lanes 0..8 of each wave) ----
    if (l < 9) {
        const int g = l / 3, q = l % 3;
        const int base = h*27 + g*9 + q*3;
        float t0 = pqc_w[base+0] * (W_MUL*0.5f);
        float t1 = pqc_w[base+1] * (W_MUL*0.5f);
        float t2 = pqc_w[base+2] * (W_MUL*0.5f);
        float c0 = __cosf(t0), s0 = __sinf(t0);
        float c1 = __cosf(t1), s1 = __sinf(t1);
        float cz = __cosf(t2), sz = __sinf(t2);
        float2 m00 = make_float2(c1*c0,  s1*s0);
        float2 m01 = make_float2(-s1*c0, -c1*s0);
        float2 m10 = make_float2(s1*c0,  -c1*s0);
        float2 m11 = make_float2(c1*c0,  -s1*s0);
        float2 em = make_float2(cz, -sz), ep = make_float2(cz, sz);
        us[h][l][0] = cmulf(em, m00);
        us[h][l][1] = cmulf(em, m01);
        us[h][l][2] = cmulf(ep, m10);
        us[h][l][3] = cmulf(ep, m11);
    }
    __syncthreads();

    // ---- Phase A2: psi = row-normalize(xq) ----
    if (t < 256) {
        const int s = t >> 3, k = t & 7;
        float ss = 0.f;
        #pragma unroll
        for (int kk = 0; kk < 8; ++kk) ss += xq[s][kk]*xq[s][kk];
        psi[s][k] = xq[s][k] * rsqrtf(ss);
    }
    // ---- Phase B2: U8 = u0 ⊗ u1 ⊗ u2 per (h,g), lane = (a,b) ----
    {
        const int r = l >> 3, c = l & 7;
        const int i0 = ((r>>2)<<1)       | (c>>2);
        const int i1 = (((r>>1)&1)<<1)   | ((c>>1)&1);
        const int i2 = ((r&1)<<1)        | (c&1);
        #pragma unroll
        for (int g = 0; g < 3; ++g)
            U8s[h][g][l] = cmulf(cmulf(us[h][g*3+0][i0], us[h][g*3+1][i1]),
                                 us[h][g*3+2][i2]);
    }
    __syncthreads();

    // ---- Phase C1: distributed Q/K/V transforms; lane = (j = l>>1, half) --
    {
        const int j = l >> 1, half = l & 1, abase = half << 2;
        // phiK components abase..abase+3 (sB = b1 sign), pair-reduce
        float kacc = 0.f;
        #pragma unroll
        for (int aa = 0; aa < 4; ++aa) {
            int a = abase + aa;
            float2 ph = make_float2(0.f, 0.f);
            #pragma unroll
            for (int b = 0; b < 8; ++b) {
                float pb = psi[j][b];
                float2 ue = U8s[h][1][a*8 + b];
                ph.x += ue.x * pb;
                ph.y += ue.y * pb;
            }
            float sign = ((a>>1) & 1) ? -1.f : 1.f;
            kacc += sign * (ph.x*ph.x + ph.y*ph.y);
        }
        kacc += __shfl_xor(kacc, 1, 64);
        if (!half) Ks[h][j] = kacc;
        // phiV components abase..abase+3
        #pragma unroll
        for (int aa = 0; aa < 4; ++aa) {
            int a = abase + aa;
            float2 ph = make_float2(0.f, 0.f);
            #pragma unroll
            for (int b = 0; b < 8; ++b) {
                float pb = psi[j][b];
                float2 ue = U8s[h][2][a*8 + b];
                ph.x += ue.x * pb;
                ph.y += ue.y * pb;
            }
            Vs[h][j][a] = ph;
        }
        // Q[h,i]: computed by the lane-pair with j == i (sA = a2^a0 sign)
        if (j == i) {
            float qacc = 0.f;
            #pragma unroll
            for (int aa = 0; aa < 4; ++aa) {
                int a = abase + aa;
                float2 ph = make_float2(0.f, 0.f);
                #pragma unroll
                for (int b = 0; b < 8; ++b) {
                    float pb = psi[i][b];
                    float2 ue = U8s[h][0][a*8 + b];
                    ph.x += ue.x * pb;
                    ph.y += ue.y * pb;
                }
                float sign = (((a>>2) ^ a) & 1) ? -1.f : 1.f;
                qacc += sign * (ph.x*ph.x + ph.y*ph.y);
            }
            qacc += __shfl_xor(qacc, 1, 64);
            if (!half) Qs[h] = qacc;
        }
    }
    __syncthreads();

    // ---- Phase C2: per lane (j, half) build chain coefficients ----
    {
        const int j = l >> 1, half = l & 1;
        const float phi = PI_F * Qs[h] * Ks[h][j];
        // u1 = rz(phi) @ ry(phi/2) @ rx(phi/2), hardware sin/cos
        float c1 = __cosf(phi*0.25f), s1 = __sinf(phi*0.25f);
        float ch = __cosf(phi*0.5f),  sh = __sinf(phi*0.5f);
        float2 em = make_float2(ch, -sh), ep = make_float2(ch, sh);
        float sc = s1*c1;
        float2 u00 = cmulf(em, make_float2(c1*c1,  s1*s1));
        float2 u01 = cmulf(em, make_float2(-sc, -sc));
        float2 u10 = cmulf(ep, make_float2(sc, -sc));
        float2 u11 = cmulf(ep, make_float2(c1*c1, -s1*s1));

        // w = (u1 ⊗ u1 ⊗ u1) phiV_j
        float2 w[8];
        #pragma unroll
        for (int b = 0; b < 8; ++b) w[b] = Vs[h][j][b];
        #pragma unroll
        for (int p = 0; p < 4; ++p) {            // qubit 0 (MSB), stride 4
            float2 lo = w[p], hi = w[p+4];
            w[p]   = caddf(cmulf(u00, lo), cmulf(u01, hi));
            w[p+4] = caddf(cmulf(u10, lo), cmulf(u11, hi));
        }
        #pragma unroll
        for (int p = 0; p < 4; ++p) {            // qubit 1, stride 2
            int i0 = ((p >> 1) << 2) | (p & 1);  // 0,1,4,5
            float2 lo = w[i0], hi = w[i0+2];
            w[i0]   = caddf(cmulf(u00, lo), cmulf(u01, hi));
            w[i0+2] = caddf(cmulf(u10, lo), cmulf(u11, hi));
        }
        #pragma unroll
        for (int p = 0; p < 4; ++p) {            // qubit 2 (LSB), stride 1
            float2 lo = w[2*p], hi = w[2*p+1];
            w[2*p]   = caddf(cmulf(u00, lo), cmulf(u01, hi));
            w[2*p+1] = caddf(cmulf(u10, lo), cmulf(u11, hi));
        }

        if (l == 0) {                             // j==0, half==0
            #pragma unroll
            for (int b = 0; b < 8; ++b) w0s[h][b] = w[b];
        }
        // C_{half}(a0,c0) = sum_{par(m)=half} w[4a0^m] conj(w[4c0^m])
        const int mset0[4] = {0,3,5,6}, mset1[4] = {1,2,4,7};
        #pragma unroll
        for (int combo = 0; combo < 4; ++combo) {
            int a0 = combo >> 1, c0 = combo & 1;
            float2 acc = make_float2(0.f, 0.f);
            #pragma unroll
            for (int tt = 0; tt < 4; ++tt) {
                int m = half ? mset1[tt] : mset0[tt];
                float2 wx = w[(a0<<2)^m], wy = w[(c0<<2)^m];
                acc.x += wx.x*wy.x + wx.y*wy.y;   // w[x]·conj(w[y])
                acc.y += wx.y*wy.x - wx.x*wy.y;
            }
            Carr[h][j][combo][half] = acc;
        }
    }
    __syncthreads();

    // ---- Phase D: serial chain (per wave); lane holds rho[a][c] ----
    {
        const int a = l >> 3, c = l & 7;
        const int combo = ((a & 1) << 1) | (c & 1);
        const int src0 = (sig3(a) << 3) | sig3(c);
        const int src1 = src0 ^ 54;               // ^ (6<<3 | 6)

        float2 wa = w0s[h][a], wc = w0s[h][c];
        float rr = wa.x*wc.x + wa.y*wc.y;         // rho = w0 w0†
        float ri = wa.y*wc.x - wa.x*wc.y;

        for (int j = 1; j < SEQL; ++j) {
            float4 Cv = *((const float4*)&Carr[h][j][combo][0]);
            float R0r = __shfl(rr, src0, 64);
            float R0i = __shfl(ri, src0, 64);
            float R1r = __shfl(rr, src1, 64);
            float R1i = __shfl(ri, src1, 64);
            float nr = Cv.x*R0r - Cv.y*R0i + Cv.z*R1r - Cv.w*R1i;
            float ni = Cv.x*R0i + Cv.y*R0r + Cv.z*R1i + Cv.w*R1r;
            rr = nr; ri = ni;
        }
        if (a == c) Zs[h][a] = rr;
    }
    __syncthreads();

    // ---- Phase E: out[i,m] = b2[m] + sum_c Zs[c>>3][c&7] * W2[m,c] ----
    {
        float acc = Zs[pE][0]*w2a.x + Zs[pE][1]*w2a.y
                  + Zs[pE][2]*w2a.z + Zs[pE][3]*w2a.w
                  + Zs[pE][4]*w2b.x + Zs[pE][5]*w2b.y
                  + Zs[pE][6]*w2b.z + Zs[pE][7]*w2b.w;
        acc += __shfl_xor(acc, 1, 64);
        acc += __shfl_xor(acc, 2, 64);
        acc += __shfl_xor(acc, 4, 64);
        if (pE == 0) out[i*64 + mE] = acc + b2m;
    }
}

extern "C" void kernel_launch(void* const* d_in, const int* in_sizes, int n_in,
                              void* d_out, int out_size, void* d_ws, size_t ws_size,
                              hipStream_t stream) {
    const float* x     = (const float*)d_in[0];
    const float* pqc_w = (const float*)d_in[1];
    const float* W1    = (const float*)d_in[2];
    const float* b1    = (const float*)d_in[3];
    const float* W2    = (const float*)d_in[4];
    const float* b2    = (const float*)d_in[5];
    // d_in[6] = edge_index (unused)

    hipLaunchKernelGGL(kfused, dim3(SEQL), dim3(512), 0, stream,
                       x, pqc_w, W1, b1, W2, b2, (float*)d_out);
}